// Round 13
// baseline (90.168 us; speedup 1.0000x reference)
//
#include <hip/hip_runtime.h>
#include <math.h>

#define IN_CH 64
#define OUT_CH 64
#define M1 32
#define M2 32
#define HH 512
#define WW 512

// ---------------- workspace layout (floats) ----------------
// F   : [512][64]  cols 0..31 = cos(2pi k h/512), cols 32..63 = sin(...)
// FA2 : [256][64]  folded stage-A table. col j<32: re, j>=32: im; mode k=kperm(j&31);
//                  value = cos(2pi k w'/512) (re) or -sin (im). kperm(q)= q<16 ? 2q : 2(q-16)+1.
// GE2 : [64][256]  folded stage-E table (see R7).
// GTI : [8 ht][32 kx][128]  interleaved phase-B trig: [2h+0]=cos(2pi kx (ht*64+h)/512),
//                  [2h+1] = -sin(...)
// XFp : [64 i][8 ht][2 reim][32 kx][32 ky']  partial h-DFT
// Gp  : [2 ic][64 o][32 kx][32 ky][2]  partial channel-mix (REAL ky order)
static const size_t OFF_F   = 0;
static const size_t OFF_FA2 = 32768;
static const size_t OFF_GE2 = 49152;
static const size_t OFF_GTI = 65536;
static const size_t OFF_XFP = 98304;
static const size_t OFF_GP  = OFF_XFP + (size_t)64*8*2048;

__device__ __forceinline__ void gload16(const float* g, float* l) {
    __builtin_amdgcn_global_load_lds(
        (const __attribute__((address_space(1))) void*)g,
        (__attribute__((address_space(3))) void*)l, 16, 0, 0);
}

__device__ __forceinline__ void fma4(float4& a, float xk, const float4 b) {
    a.x = __builtin_fmaf(xk, b.x, a.x);
    a.y = __builtin_fmaf(xk, b.y, a.y);
    a.z = __builtin_fmaf(xk, b.z, a.z);
    a.w = __builtin_fmaf(xk, b.w, a.w);
}

__global__ void build_table(float* __restrict__ F, float* __restrict__ FA2,
                            float* __restrict__ GE2, float* __restrict__ GTI) {
    int idx = blockIdx.x * 256 + threadIdx.x;      // 0..32767
    const float c0 = 6.283185307179586f / 512.0f;
    {   // F
        int w = idx >> 6, j = idx & 63, k = j & 31;
        int m = (k * w) & 511;
        float s, c;
        sincosf(c0 * (float)m, &s, &c);
        F[idx] = (j < 32) ? c : s;
    }
    {   // GTI [8][32][128]
        int ht = idx >> 12, kx = (idx >> 7) & 31, pos = idx & 127;
        int h = pos >> 1, comp = pos & 1;
        int m = (kx * (ht * 64 + h)) & 511;
        float s, c;
        sincosf(c0 * (float)m, &s, &c);
        GTI[idx] = comp ? -s : c;
    }
    if (idx < 16384) {   // FA2 [256][64]
        int wp = idx >> 6, j = idx & 63, q = j & 31;
        int k = (q < 16) ? 2 * q : 2 * (q - 16) + 1;
        int m = (k * wp) & 511;
        float s, c;
        sincosf(c0 * (float)m, &s, &c);
        FA2[idx] = (j < 32) ? c : -s;
    }
    if (idx < 16384) {   // GE2 [64][256]
        int cc = idx >> 8, wp = idx & 255;
        int base = cc & 15, parity = (cc >> 5) & 1, isIm = (cc >> 4) & 1;
        int k = 2 * base + parity;
        int m = (k * wp) & 511;
        float s, c;
        sincosf(c0 * (float)m, &s, &c);
        GE2[idx] = isIm ? -s : c;
    }
}

// Fused A+B, wave-K-split 32:1 design. grid 512: i = bid>>3, ht = bid&7 (64 h-rows).
// Each wave computes a PARTIAL of the full 64x64 Xw tile over its K-quarter
// (4 quads/chunk), acc 4 rows x 16 cols per thread. A (e/o) from LDS (4 b128/quad),
// B (FA2) from VMEM L1 broadcast (16 b128/quad, 4 distinct 64B lines each).
// 3-round LDS tree reduction, then phase B with interleaved GTI (3 LDS instr/hh).
__global__ __launch_bounds__(256) void fusedAB(const float* __restrict__ x,
                                               const float* __restrict__ FA2,
                                               const float* __restrict__ GTI,
                                               float* __restrict__ XFp) {
    __shared__ __align__(16) float xeo[8712];   // e [64][68] @0, o @4360; later partials/Xw
    __shared__ __align__(16) float bs[4352];    // phase B: gti [32][132]
    int t = threadIdx.x;
    int lane = t & 63, wid = t >> 6;
    int tx = lane & 3, ty = lane >> 2;          // 4 col-groups x 16 cols, 16 row-groups x 4
    int i = blockIdx.x >> 3, ht = blockIdx.x & 7;
    int h0 = ht * 64;

    float4 acc4[4][4];
#pragma unroll
    for (int r = 0; r < 4; ++r)
#pragma unroll
        for (int c = 0; c < 4; ++c) acc4[r][c] = make_float4(0.f, 0.f, 0.f, 0.f);

    const float* xbase = &x[((size_t)i * 512 + h0) * 512];
    float4 ra[4], rb[4];
    // prologue: x chunk0 -> regs
#pragma unroll
    for (int p = 0; p < 4; ++p) {
        int flat = p * 1024 + t * 4;
        int rl = flat >> 6, c4 = flat & 63;
        const float* xr = xbase + (size_t)rl * 512 + c4;
        ra[p] = *(const float4*)xr;
        rb[p] = *(const float4*)(xr + 256);
    }

    const float* xsb = &xeo[(tx & 1) ? 4360 : 0];   // odd-parity cols read o
    int kbase = wid * 16;
    for (int tt = 0; tt < 4; ++tt) {
        if (tt) __syncthreads();       // readers of prev chunk done
#pragma unroll
        for (int p = 0; p < 4; ++p) {
            int flat = p * 1024 + t * 4;
            int rl = flat >> 6, c4 = flat & 63;
            *(float4*)&xeo[rl * 68 + c4] =
                make_float4(ra[p].x + rb[p].x, ra[p].y + rb[p].y,
                            ra[p].z + rb[p].z, ra[p].w + rb[p].w);
            *(float4*)&xeo[4360 + rl * 68 + c4] =
                make_float4(ra[p].x - rb[p].x, ra[p].y - rb[p].y,
                            ra[p].z - rb[p].z, ra[p].w - rb[p].w);
        }
        __syncthreads();               // e/o visible
        if (tt < 3) {                  // prefetch next chunk during compute
            int w0n = (tt + 1) * 64;
#pragma unroll
            for (int p = 0; p < 4; ++p) {
                int flat = p * 1024 + t * 4;
                int rl = flat >> 6, c4 = flat & 63;
                const float* xr = xbase + (size_t)rl * 512 + w0n + c4;
                ra[p] = *(const float4*)xr;
                rb[p] = *(const float4*)(xr + 256);
            }
        }
#pragma unroll
        for (int q = 0; q < 4; ++q) {
            int kq = kbase + q * 4;
            float4 av[4];
#pragma unroll
            for (int r = 0; r < 4; ++r)
                av[r] = *(const float4*)&xsb[(ty * 4 + r) * 68 + kq];
            const float* fb = FA2 + ((size_t)tt * 64 + kq) * 64 + tx * 16;
#pragma unroll
            for (int kk = 0; kk < 4; ++kk) {
                float4 b0 = *(const float4*)(fb + kk * 64);
                float4 b1 = *(const float4*)(fb + kk * 64 + 4);
                float4 b2 = *(const float4*)(fb + kk * 64 + 8);
                float4 b3 = *(const float4*)(fb + kk * 64 + 12);
#pragma unroll
                for (int r = 0; r < 4; ++r) {
                    float xk = (kk == 0) ? av[r].x : (kk == 1) ? av[r].y
                             : (kk == 2) ? av[r].z : av[r].w;
                    fma4(acc4[r][0], xk, b0);
                    fma4(acc4[r][1], xk, b1);
                    fma4(acc4[r][2], xk, b2);
                    fma4(acc4[r][3], xk, b3);
                }
            }
        }
    }
    __syncthreads();   // compute done reading xeo

    // stage gti into bs; waves 2,3 write partials
#pragma unroll
    for (int p = 0; p < 4; ++p) {
        int flat = p * 1024 + t * 4;
        int kx = flat >> 7, pos = flat & 127;
        *(float4*)&bs[kx * 132 + pos] = *(const float4*)&GTI[(size_t)ht * 4096 + flat];
    }
    if (wid >= 2) {
        float* reg = &xeo[(wid - 2) * 4360];
#pragma unroll
        for (int r = 0; r < 4; ++r)
#pragma unroll
            for (int c = 0; c < 4; ++c)
                *(float4*)&reg[(ty * 4 + r) * 68 + tx * 16 + c * 4] = acc4[r][c];
    }
    __syncthreads();
    if (wid < 2) {
        const float* reg = &xeo[wid * 4360];
#pragma unroll
        for (int r = 0; r < 4; ++r)
#pragma unroll
            for (int c = 0; c < 4; ++c) {
                float4 v = *(const float4*)&reg[(ty * 4 + r) * 68 + tx * 16 + c * 4];
                acc4[r][c].x += v.x; acc4[r][c].y += v.y;
                acc4[r][c].z += v.z; acc4[r][c].w += v.w;
            }
    }
    __syncthreads();
    if (wid == 1) {
#pragma unroll
        for (int r = 0; r < 4; ++r)
#pragma unroll
            for (int c = 0; c < 4; ++c)
                *(float4*)&xeo[(ty * 4 + r) * 68 + tx * 16 + c * 4] = acc4[r][c];
    }
    __syncthreads();
    if (wid == 0) {
#pragma unroll
        for (int r = 0; r < 4; ++r)
#pragma unroll
            for (int c = 0; c < 4; ++c) {
                float* p = &xeo[(ty * 4 + r) * 68 + tx * 16 + c * 4];
                float4 v = *(const float4*)p;
                v.x += acc4[r][c].x; v.y += acc4[r][c].y;
                v.z += acc4[r][c].z; v.w += acc4[r][c].w;
                *(float4*)p = v;
            }
    }
    __syncthreads();

    // Phase B: xw = xeo[64][68]; gti = bs[32][132] (cos,-sin interleaved)
    int kx = t >> 3, kg = t & 7;
    float rr[4] = {0.f, 0.f, 0.f, 0.f};
    float ii[4] = {0.f, 0.f, 0.f, 0.f};
#pragma unroll 4
    for (int hh = 0; hh < 64; ++hh) {
        float2 cs = *(const float2*)&bs[kx * 132 + 2 * hh];   // (cos, -sin)
        float4 xr4 = *(const float4*)&xeo[hh * 68 + kg * 4];
        float4 xi4 = *(const float4*)&xeo[hh * 68 + 32 + kg * 4];
        rr[0] = __builtin_fmaf(xr4.x, cs.x, rr[0]); rr[0] = __builtin_fmaf(xi4.x, -cs.y, rr[0]);
        rr[1] = __builtin_fmaf(xr4.y, cs.x, rr[1]); rr[1] = __builtin_fmaf(xi4.y, -cs.y, rr[1]);
        rr[2] = __builtin_fmaf(xr4.z, cs.x, rr[2]); rr[2] = __builtin_fmaf(xi4.z, -cs.y, rr[2]);
        rr[3] = __builtin_fmaf(xr4.w, cs.x, rr[3]); rr[3] = __builtin_fmaf(xi4.w, -cs.y, rr[3]);
        ii[0] = __builtin_fmaf(xi4.x, cs.x, ii[0]); ii[0] = __builtin_fmaf(xr4.x, cs.y, ii[0]);
        ii[1] = __builtin_fmaf(xi4.y, cs.x, ii[1]); ii[1] = __builtin_fmaf(xr4.y, cs.y, ii[1]);
        ii[2] = __builtin_fmaf(xi4.z, cs.x, ii[2]); ii[2] = __builtin_fmaf(xr4.z, cs.y, ii[2]);
        ii[3] = __builtin_fmaf(xi4.w, cs.x, ii[3]); ii[3] = __builtin_fmaf(xr4.w, cs.y, ii[3]);
    }
    size_t base = ((size_t)i * 8 + ht) * 2048;
    *(float4*)&XFp[base + t * 4]        = make_float4(rr[0], rr[1], rr[2], rr[3]);
    *(float4*)&XFp[base + 1024 + t * 4] = make_float4(ii[0], ii[1], ii[2], ii[3]);
}

// Stage C: partial channel mix, i split in 2. grid 512. (R7 verbatim)
__global__ __launch_bounds__(256) void stageC(const float* __restrict__ XFp,
                                              const float* __restrict__ Wr,
                                              const float* __restrict__ Wi,
                                              float* __restrict__ Gp) {
    __shared__ float sxr[32][33];   // [ky'][i']
    __shared__ float sxi[32][33];
    int t = threadIdx.x;
    int kx = blockIdx.x & 31, oc = (blockIdx.x >> 5) & 7, ic = blockIdx.x >> 8;
#pragma unroll
    for (int q = 0; q < 4; ++q) {
        int idx = q * 256 + t;               // 0..1023 = i'*32 + ky'(storage)
        int ip = idx >> 5, kys = idx & 31;
        int i = ic * 32 + ip;
        float sr = 0.f, si = 0.f;
#pragma unroll
        for (int ht = 0; ht < 8; ++ht) {
            size_t base = ((size_t)i * 8 + ht) * 2048 + kx * 32 + kys;
            sr += XFp[base];
            si += XFp[base + 1024];
        }
        sxr[kys][ip] = sr;
        sxi[kys][ip] = si;
    }
    __syncthreads();
    int ky = t & 31, ol = t >> 5;            // REAL ky
    int kyp = (ky & 1) ? 16 + (ky >> 1) : (ky >> 1);
    int o = oc * 8 + ol;
    float lr = 0.f, li = 0.f;
#pragma unroll 4
    for (int ip = 0; ip < 32; ++ip) {
        float a = sxr[kyp][ip];
        float b = sxi[kyp][ip];
        size_t widx = ((size_t)(ic * 32 + ip) * 64 + o) * 1024 + kx * 32 + ky;
        float wrv = Wr[widx];
        float wiv = Wi[widx];
        lr = __builtin_fmaf(a, wrv, lr); lr = __builtin_fmaf(-b, wiv, lr);
        li = __builtin_fmaf(a, wiv, li); li = __builtin_fmaf(b, wrv, li);
    }
    size_t gidx = ((size_t)ic * 65536 + (size_t)o * 1024 + kx * 32 + ky) * 2;
    Gp[gidx]     = lr;
    Gp[gidx + 1] = li;
}

// Fused (reduceG +) D + E. grid 512: o = bid>>3, ht = bid&7. (R7 verbatim)
__global__ __launch_bounds__(256) void fusedDE(const float* __restrict__ Fc,
                                               const float* __restrict__ Gp,
                                               const float* __restrict__ GE2,
                                               float* __restrict__ out) {
    __shared__ __align__(16) float as[4096];   // F-tile (src-swizzled), then Z (XOR-swizzled)
    __shared__ __align__(16) float bs[4096];   // G [64m][64j'], then GE2 tiles
    int t = threadIdx.x, tx = t & 15, ty = t >> 4;
    int o = blockIdx.x >> 3, ht = blockIdx.x & 7;
    int sw = (ty & 3) << 2;

    const float2* gp2 = (const float2*)Gp;
#pragma unroll
    for (int q = 0; q < 4; ++q) {
        int iq = q * 256 + t;                 // 0..1023 = kx*32+ky (REAL ky)
        int ky = iq & 31, kx = iq >> 5;
        float2 g0 = gp2[(size_t)o * 1024 + iq];
        float2 g1 = gp2[(size_t)65536 + (size_t)o * 1024 + iq];
        float sc = ((ky == 0) ? 1.0f : 2.0f) * (1.0f / 262144.0f);
        float lr = (g0.x + g1.x) * sc;
        float li = (g0.y + g1.y) * sc;
        int pp = ky & 1, qq = ky >> 1;
        int colR = pp * 32 + qq, colI = pp * 32 + 16 + qq;
        bs[kx * 64 + colR]        = lr;
        bs[(32 + kx) * 64 + colR] = -li;
        bs[kx * 64 + colI]        = li;
        bs[(32 + kx) * 64 + colI] = lr;
    }
#pragma unroll
    for (int p = 0; p < 4; ++p) {
        int flat = p * 1024 + t * 4;
        int s16 = flat >> 2;
        int row = s16 >> 4, cp = s16 & 15;
        int cg = cp ^ ((row >> 2) & 3);
        gload16(Fc + (size_t)(ht * 64 + row) * 64 + cg * 4, &as[flat]);
    }
    __syncthreads();

    float acc[4][4] = {};
#pragma unroll 4
    for (int k0 = 0; k0 < 64; k0 += 4) {
        int ka = k0 ^ sw;
        float4 av[4], bv[4];
#pragma unroll
        for (int r = 0; r < 4; ++r)
            av[r] = *(const float4*)&as[(ty * 4 + r) * 64 + ka];
#pragma unroll
        for (int kk = 0; kk < 4; ++kk)
            bv[kk] = *(const float4*)&bs[(k0 + kk) * 64 + tx * 4];
#pragma unroll
        for (int kk = 0; kk < 4; ++kk)
#pragma unroll
            for (int r = 0; r < 4; ++r) {
                float xk = (kk == 0) ? av[r].x : (kk == 1) ? av[r].y
                         : (kk == 2) ? av[r].z : av[r].w;
                acc[r][0] = __builtin_fmaf(xk, bv[kk].x, acc[r][0]);
                acc[r][1] = __builtin_fmaf(xk, bv[kk].y, acc[r][1]);
                acc[r][2] = __builtin_fmaf(xk, bv[kk].z, acc[r][2]);
                acc[r][3] = __builtin_fmaf(xk, bv[kk].w, acc[r][3]);
            }
    }
    __syncthreads();

#pragma unroll
    for (int r = 0; r < 4; ++r) {
        int row = ty * 4 + r;
        int cg = tx ^ ((row >> 2) & 3);
        *(float4*)&as[row * 64 + cg * 4] =
            make_float4(acc[r][0], acc[r][1], acc[r][2], acc[r][3]);
    }

    for (int cb = 0; cb < 4; ++cb) {
        __syncthreads();
#pragma unroll
        for (int p = 0; p < 4; ++p) {
            int flat = p * 1024 + t * 4;
            int brow = flat >> 6, bcol = flat & 63;
            gload16(GE2 + (size_t)brow * 256 + cb * 64 + bcol, &bs[flat]);
        }
        __syncthreads();
        float pa[4][4] = {}, pb[4][4] = {};
#pragma unroll 4
        for (int k0 = 0; k0 < 32; k0 += 4) {
            int kae = k0 ^ sw, kao = 32 + (k0 ^ sw);
            float4 av[4], bv[4], aw[4], bw[4];
#pragma unroll
            for (int r = 0; r < 4; ++r) {
                av[r] = *(const float4*)&as[(ty * 4 + r) * 64 + kae];
                aw[r] = *(const float4*)&as[(ty * 4 + r) * 64 + kao];
            }
#pragma unroll
            for (int kk = 0; kk < 4; ++kk) {
                bv[kk] = *(const float4*)&bs[(k0 + kk) * 64 + tx * 4];
                bw[kk] = *(const float4*)&bs[(32 + k0 + kk) * 64 + tx * 4];
            }
#pragma unroll
            for (int kk = 0; kk < 4; ++kk)
#pragma unroll
                for (int r = 0; r < 4; ++r) {
                    float xe = (kk == 0) ? av[r].x : (kk == 1) ? av[r].y
                             : (kk == 2) ? av[r].z : av[r].w;
                    float xo = (kk == 0) ? aw[r].x : (kk == 1) ? aw[r].y
                             : (kk == 2) ? aw[r].z : aw[r].w;
                    pa[r][0] = __builtin_fmaf(xe, bv[kk].x, pa[r][0]);
                    pa[r][1] = __builtin_fmaf(xe, bv[kk].y, pa[r][1]);
                    pa[r][2] = __builtin_fmaf(xe, bv[kk].z, pa[r][2]);
                    pa[r][3] = __builtin_fmaf(xe, bv[kk].w, pa[r][3]);
                    pb[r][0] = __builtin_fmaf(xo, bw[kk].x, pb[r][0]);
                    pb[r][1] = __builtin_fmaf(xo, bw[kk].y, pb[r][1]);
                    pb[r][2] = __builtin_fmaf(xo, bw[kk].z, pb[r][2]);
                    pb[r][3] = __builtin_fmaf(xo, bw[kk].w, pb[r][3]);
                }
        }
#pragma unroll
        for (int r = 0; r < 4; ++r) {
            float* orow = out + (size_t)(o * 512 + ht * 64 + ty * 4 + r) * 512;
            *(float4*)&orow[cb * 64 + tx * 4] =
                make_float4(pa[r][0] + pb[r][0], pa[r][1] + pb[r][1],
                            pa[r][2] + pb[r][2], pa[r][3] + pb[r][3]);
            *(float4*)&orow[256 + cb * 64 + tx * 4] =
                make_float4(pa[r][0] - pb[r][0], pa[r][1] - pb[r][1],
                            pa[r][2] - pb[r][2], pa[r][3] - pb[r][3]);
        }
    }
}

extern "C" void kernel_launch(void* const* d_in, const int* in_sizes, int n_in,
                              void* d_out, int out_size, void* d_ws, size_t ws_size,
                              hipStream_t stream) {
    const float* x  = (const float*)d_in[0];
    const float* Wr = (const float*)d_in[1];
    const float* Wi = (const float*)d_in[2];
    float* out = (float*)d_out;
    float* ws  = (float*)d_ws;

    float* F   = ws + OFF_F;
    float* FA2 = ws + OFF_FA2;
    float* GE2 = ws + OFF_GE2;
    float* GTI = ws + OFF_GTI;
    float* XFp = ws + OFF_XFP;
    float* Gp  = ws + OFF_GP;

    build_table<<<128, 256, 0, stream>>>(F, FA2, GE2, GTI);
    fusedAB<<<512, 256, 0, stream>>>(x, FA2, GTI, XFp);
    stageC<<<512, 256, 0, stream>>>(XFp, Wr, Wi, Gp);
    fusedDE<<<512, 256, 0, stream>>>(F, Gp, GE2, out);
}

// Round 14
// 72.098 us; speedup vs baseline: 1.2506x; 1.2506x over previous
//
#include <hip/hip_runtime.h>
#include <math.h>

#define IN_CH 64
#define OUT_CH 64
#define M1 32
#define M2 32
#define HH 512
#define WW 512

// ---------------- workspace layout (floats) ----------------
// F   : [512][64]  cols 0..31 = cos(2pi k h/512), cols 32..63 = sin(...)
// FA2 : [256][64]  folded stage-A table. col j<32: re, j>=32: im; mode k=kperm(j&31);
//                  value = cos(2pi k w'/512) (re) or -sin (im). kperm(q)= q<16 ? 2q : 2(q-16)+1.
// GE2 : [64][256]  folded stage-E table. row c: c<16 re k=2c; 16..31 im k=2(c-16);
//                  32..47 re k=2(c-32)+1; 48..63 im k=2(c-48)+1. cos (re) / -sin (im).
// GT  : [64][512]  row j<32: cos(2pi j t/512); row j>=32: -sin(...)
// XFp : [64 i][8 ht][2 reim][32 kx][32 ky']  partial h-DFT
// Gp  : [2 ic][64 o][32 kx][32 ky][2]  partial channel-mix (REAL ky order)
static const size_t OFF_F   = 0;
static const size_t OFF_FA2 = 32768;
static const size_t OFF_GE2 = 49152;
static const size_t OFF_GT  = 65536;
static const size_t OFF_XFP = 98304;
static const size_t OFF_GP  = OFF_XFP + (size_t)64*8*2048;

__device__ __forceinline__ void gload16(const float* g, float* l) {
    __builtin_amdgcn_global_load_lds(
        (const __attribute__((address_space(1))) void*)g,
        (__attribute__((address_space(3))) void*)l, 16, 0, 0);
}

__global__ void build_table(float* __restrict__ F, float* __restrict__ FA2,
                            float* __restrict__ GE2, float* __restrict__ GT) {
    int idx = blockIdx.x * 256 + threadIdx.x;      // 0..32767
    const float c0 = 6.283185307179586f / 512.0f;
    {   // F + GT
        int w = idx >> 6, j = idx & 63, k = j & 31;
        int m = (k * w) & 511;
        float s, c;
        sincosf(c0 * (float)m, &s, &c);
        F[idx] = (j < 32) ? c : s;
        GT[(size_t)j * 512 + w] = (j < 32) ? c : -s;
    }
    if (idx < 16384) {   // FA2 [256][64]
        int wp = idx >> 6, j = idx & 63, q = j & 31;
        int k = (q < 16) ? 2 * q : 2 * (q - 16) + 1;
        int m = (k * wp) & 511;
        float s, c;
        sincosf(c0 * (float)m, &s, &c);
        FA2[idx] = (j < 32) ? c : -s;
    }
    if (idx < 16384) {   // GE2 [64][256]
        int cc = idx >> 8, wp = idx & 255;
        int base = cc & 15, parity = (cc >> 5) & 1, isIm = (cc >> 4) & 1;
        int k = 2 * base + parity;
        int m = (k * wp) & 511;
        float s, c;
        sincosf(c0 * (float)m, &s, &c);
        GE2[idx] = isIm ? -s : c;
    }
}

// Fused A+B — R7 structure verbatim, with one change: x loads for chunk tt+1
// (and the GT slice for phase B) are ISSUED right after the top barrier and
// consumed at the next iteration's e/o write, hiding the ~900cy load latency
// under compute. LDS identical to R7 (52.3 KB -> 3 blocks/CU); bs single-buffered.
__global__ __launch_bounds__(256) void fusedAB(const float* __restrict__ x,
                                               const float* __restrict__ FA2,
                                               const float* __restrict__ GT,
                                               float* __restrict__ XFp) {
    __shared__ __align__(16) float xeo[8712];   // e [64][68] @0; o @4360; later xw [64][68]
    __shared__ __align__(16) float bs[4352];    // FA2 tile linear [64][64]; later gt [64][68]
    int t = threadIdx.x, tx = t & 15, ty = t >> 4;
    int i = blockIdx.x >> 3, ht = blockIdx.x & 7;
    int h0 = ht * 64;
    int c4 = tx * 4;

    const float* xrow[4];
    float4 ra[4], rb[4], gtr[4];
#pragma unroll
    for (int p = 0; p < 4; ++p) {               // prologue: chunk 0 -> regs
        xrow[p] = &x[((size_t)i * 512 + h0 + p * 16 + ty) * 512 + c4];
        ra[p] = *(const float4*)(xrow[p]);
        rb[p] = *(const float4*)(xrow[p] + 256);
    }

    float acc[4][4] = {};
    const float* xsb = &xeo[(tx & 4) ? 4360 : 0];   // cols 16..31,48..63: odd-k -> o
    for (int tt = 0; tt < 4; ++tt) {
        // write e/o from regs; issue FA2 gload for this chunk (bs free since last sync)
#pragma unroll
        for (int p = 0; p < 4; ++p) {
            int rl = p * 16 + ty;
            *(float4*)&xeo[rl * 68 + c4] =
                make_float4(ra[p].x + rb[p].x, ra[p].y + rb[p].y,
                            ra[p].z + rb[p].z, ra[p].w + rb[p].w);
            *(float4*)&xeo[4360 + rl * 68 + c4] =
                make_float4(ra[p].x - rb[p].x, ra[p].y - rb[p].y,
                            ra[p].z - rb[p].z, ra[p].w - rb[p].w);
            gload16(FA2 + (size_t)(tt * 64 + rl) * 64 + c4, &bs[p * 1024 + t * 4]);
        }
        __syncthreads();             // e/o visible; bs drained
        if (tt < 3) {                // issue next chunk's x loads: land during compute
#pragma unroll
            for (int p = 0; p < 4; ++p) {
                ra[p] = *(const float4*)(xrow[p] + (tt + 1) * 64);
                rb[p] = *(const float4*)(xrow[p] + (tt + 1) * 64 + 256);
            }
        } else {                     // prefetch GT slice for phase B into regs
#pragma unroll
            for (int p = 0; p < 4; ++p) {
                int flat = p * 1024 + t * 4;
                gtr[p] = *(const float4*)&GT[(size_t)(flat >> 6) * 512 + h0 + (flat & 63)];
            }
        }
#pragma unroll 4
        for (int k0 = 0; k0 < 64; k0 += 4) {
            float4 av[4], bv[4];
#pragma unroll
            for (int r = 0; r < 4; ++r)
                av[r] = *(const float4*)&xsb[(ty * 4 + r) * 68 + k0];
#pragma unroll
            for (int kk = 0; kk < 4; ++kk)
                bv[kk] = *(const float4*)&bs[(k0 + kk) * 64 + tx * 4];
#pragma unroll
            for (int kk = 0; kk < 4; ++kk)
#pragma unroll
                for (int r = 0; r < 4; ++r) {
                    float xk = (kk == 0) ? av[r].x : (kk == 1) ? av[r].y
                             : (kk == 2) ? av[r].z : av[r].w;
                    acc[r][0] = __builtin_fmaf(xk, bv[kk].x, acc[r][0]);
                    acc[r][1] = __builtin_fmaf(xk, bv[kk].y, acc[r][1]);
                    acc[r][2] = __builtin_fmaf(xk, bv[kk].z, acc[r][2]);
                    acc[r][3] = __builtin_fmaf(xk, bv[kk].w, acc[r][3]);
                }
        }
        __syncthreads();             // readers done before next write
    }

    // store Xw tile into xeo ([64][68]) and gt regs into bs ([64][68])
#pragma unroll
    for (int r = 0; r < 4; ++r)
        *(float4*)&xeo[(ty * 4 + r) * 68 + tx * 4] =
            make_float4(acc[r][0], acc[r][1], acc[r][2], acc[r][3]);
#pragma unroll
    for (int p = 0; p < 4; ++p) {
        int flat = p * 1024 + t * 4;
        int j = flat >> 6, hc = flat & 63;
        *(float4*)&bs[j * 68 + hc] = gtr[p];
    }
    __syncthreads();

    // Phase B (R7 verbatim)
    int kx = t >> 3, kg = t & 7;
    float rr[4] = {0.f, 0.f, 0.f, 0.f};
    float ii[4] = {0.f, 0.f, 0.f, 0.f};
#pragma unroll 4
    for (int hh = 0; hh < 64; ++hh) {
        float cv = bs[kx * 68 + hh];
        float sv = bs[(kx + 32) * 68 + hh];          // = -sin
        float4 xr4 = *(const float4*)&xeo[hh * 68 + kg * 4];
        float4 xi4 = *(const float4*)&xeo[hh * 68 + 32 + kg * 4];
        rr[0] = __builtin_fmaf(xr4.x, cv, rr[0]); rr[0] = __builtin_fmaf(xi4.x, -sv, rr[0]);
        rr[1] = __builtin_fmaf(xr4.y, cv, rr[1]); rr[1] = __builtin_fmaf(xi4.y, -sv, rr[1]);
        rr[2] = __builtin_fmaf(xr4.z, cv, rr[2]); rr[2] = __builtin_fmaf(xi4.z, -sv, rr[2]);
        rr[3] = __builtin_fmaf(xr4.w, cv, rr[3]); rr[3] = __builtin_fmaf(xi4.w, -sv, rr[3]);
        ii[0] = __builtin_fmaf(xi4.x, cv, ii[0]); ii[0] = __builtin_fmaf(xr4.x, sv, ii[0]);
        ii[1] = __builtin_fmaf(xi4.y, cv, ii[1]); ii[1] = __builtin_fmaf(xr4.y, sv, ii[1]);
        ii[2] = __builtin_fmaf(xi4.z, cv, ii[2]); ii[2] = __builtin_fmaf(xr4.z, sv, ii[2]);
        ii[3] = __builtin_fmaf(xi4.w, cv, ii[3]); ii[3] = __builtin_fmaf(xr4.w, sv, ii[3]);
    }
    size_t base = ((size_t)i * 8 + ht) * 2048;
    *(float4*)&XFp[base + t * 4]        = make_float4(rr[0], rr[1], rr[2], rr[3]);
    *(float4*)&XFp[base + 1024 + t * 4] = make_float4(ii[0], ii[1], ii[2], ii[3]);
}

// Stage C: partial channel mix, i split in 2. grid 512. (R7 verbatim)
__global__ __launch_bounds__(256) void stageC(const float* __restrict__ XFp,
                                              const float* __restrict__ Wr,
                                              const float* __restrict__ Wi,
                                              float* __restrict__ Gp) {
    __shared__ float sxr[32][33];   // [ky'][i']
    __shared__ float sxi[32][33];
    int t = threadIdx.x;
    int kx = blockIdx.x & 31, oc = (blockIdx.x >> 5) & 7, ic = blockIdx.x >> 8;
#pragma unroll
    for (int q = 0; q < 4; ++q) {
        int idx = q * 256 + t;               // 0..1023 = i'*32 + ky'(storage)
        int ip = idx >> 5, kys = idx & 31;
        int i = ic * 32 + ip;
        float sr = 0.f, si = 0.f;
#pragma unroll
        for (int ht = 0; ht < 8; ++ht) {
            size_t base = ((size_t)i * 8 + ht) * 2048 + kx * 32 + kys;
            sr += XFp[base];
            si += XFp[base + 1024];
        }
        sxr[kys][ip] = sr;
        sxi[kys][ip] = si;
    }
    __syncthreads();
    int ky = t & 31, ol = t >> 5;            // REAL ky
    int kyp = (ky & 1) ? 16 + (ky >> 1) : (ky >> 1);
    int o = oc * 8 + ol;
    float lr = 0.f, li = 0.f;
#pragma unroll 4
    for (int ip = 0; ip < 32; ++ip) {
        float a = sxr[kyp][ip];
        float b = sxi[kyp][ip];
        size_t widx = ((size_t)(ic * 32 + ip) * 64 + o) * 1024 + kx * 32 + ky;
        float wrv = Wr[widx];
        float wiv = Wi[widx];
        lr = __builtin_fmaf(a, wrv, lr); lr = __builtin_fmaf(-b, wiv, lr);
        li = __builtin_fmaf(a, wiv, li); li = __builtin_fmaf(b, wrv, li);
    }
    size_t gidx = ((size_t)ic * 65536 + (size_t)o * 1024 + kx * 32 + ky) * 2;
    Gp[gidx]     = lr;
    Gp[gidx + 1] = li;
}

// Fused (reduceG +) D + E. grid 512: o = bid>>3, ht = bid&7. (R7 verbatim)
__global__ __launch_bounds__(256) void fusedDE(const float* __restrict__ Fc,
                                               const float* __restrict__ Gp,
                                               const float* __restrict__ GE2,
                                               float* __restrict__ out) {
    __shared__ __align__(16) float as[4096];   // F-tile (src-swizzled), then Z (XOR-swizzled)
    __shared__ __align__(16) float bs[4096];   // G [64m][64j'], then GE2 tiles
    int t = threadIdx.x, tx = t & 15, ty = t >> 4;
    int o = blockIdx.x >> 3, ht = blockIdx.x & 7;
    int sw = (ty & 3) << 2;

    const float2* gp2 = (const float2*)Gp;
#pragma unroll
    for (int q = 0; q < 4; ++q) {
        int iq = q * 256 + t;                 // 0..1023 = kx*32+ky (REAL ky)
        int ky = iq & 31, kx = iq >> 5;
        float2 g0 = gp2[(size_t)o * 1024 + iq];
        float2 g1 = gp2[(size_t)65536 + (size_t)o * 1024 + iq];
        float sc = ((ky == 0) ? 1.0f : 2.0f) * (1.0f / 262144.0f);
        float lr = (g0.x + g1.x) * sc;
        float li = (g0.y + g1.y) * sc;
        int pp = ky & 1, qq = ky >> 1;
        int colR = pp * 32 + qq, colI = pp * 32 + 16 + qq;
        bs[kx * 64 + colR]        = lr;
        bs[(32 + kx) * 64 + colR] = -li;
        bs[kx * 64 + colI]        = li;
        bs[(32 + kx) * 64 + colI] = lr;
    }
#pragma unroll
    for (int p = 0; p < 4; ++p) {
        int flat = p * 1024 + t * 4;
        int s16 = flat >> 2;
        int row = s16 >> 4, cp = s16 & 15;
        int cg = cp ^ ((row >> 2) & 3);
        gload16(Fc + (size_t)(ht * 64 + row) * 64 + cg * 4, &as[flat]);
    }
    __syncthreads();

    float acc[4][4] = {};
#pragma unroll 4
    for (int k0 = 0; k0 < 64; k0 += 4) {
        int ka = k0 ^ sw;
        float4 av[4], bv[4];
#pragma unroll
        for (int r = 0; r < 4; ++r)
            av[r] = *(const float4*)&as[(ty * 4 + r) * 64 + ka];
#pragma unroll
        for (int kk = 0; kk < 4; ++kk)
            bv[kk] = *(const float4*)&bs[(k0 + kk) * 64 + tx * 4];
#pragma unroll
        for (int kk = 0; kk < 4; ++kk)
#pragma unroll
            for (int r = 0; r < 4; ++r) {
                float xk = (kk == 0) ? av[r].x : (kk == 1) ? av[r].y
                         : (kk == 2) ? av[r].z : av[r].w;
                acc[r][0] = __builtin_fmaf(xk, bv[kk].x, acc[r][0]);
                acc[r][1] = __builtin_fmaf(xk, bv[kk].y, acc[r][1]);
                acc[r][2] = __builtin_fmaf(xk, bv[kk].z, acc[r][2]);
                acc[r][3] = __builtin_fmaf(xk, bv[kk].w, acc[r][3]);
            }
    }
    __syncthreads();

#pragma unroll
    for (int r = 0; r < 4; ++r) {
        int row = ty * 4 + r;
        int cg = tx ^ ((row >> 2) & 3);
        *(float4*)&as[row * 64 + cg * 4] =
            make_float4(acc[r][0], acc[r][1], acc[r][2], acc[r][3]);
    }

    for (int cb = 0; cb < 4; ++cb) {
        __syncthreads();
#pragma unroll
        for (int p = 0; p < 4; ++p) {
            int flat = p * 1024 + t * 4;
            int brow = flat >> 6, bcol = flat & 63;
            gload16(GE2 + (size_t)brow * 256 + cb * 64 + bcol, &bs[flat]);
        }
        __syncthreads();
        float pa[4][4] = {}, pb[4][4] = {};
#pragma unroll 4
        for (int k0 = 0; k0 < 32; k0 += 4) {
            int kae = k0 ^ sw, kao = 32 + (k0 ^ sw);
            float4 av[4], bv[4], aw[4], bw[4];
#pragma unroll
            for (int r = 0; r < 4; ++r) {
                av[r] = *(const float4*)&as[(ty * 4 + r) * 64 + kae];
                aw[r] = *(const float4*)&as[(ty * 4 + r) * 64 + kao];
            }
#pragma unroll
            for (int kk = 0; kk < 4; ++kk) {
                bv[kk] = *(const float4*)&bs[(k0 + kk) * 64 + tx * 4];
                bw[kk] = *(const float4*)&bs[(32 + k0 + kk) * 64 + tx * 4];
            }
#pragma unroll
            for (int kk = 0; kk < 4; ++kk)
#pragma unroll
                for (int r = 0; r < 4; ++r) {
                    float xe = (kk == 0) ? av[r].x : (kk == 1) ? av[r].y
                             : (kk == 2) ? av[r].z : av[r].w;
                    float xo = (kk == 0) ? aw[r].x : (kk == 1) ? aw[r].y
                             : (kk == 2) ? aw[r].z : aw[r].w;
                    pa[r][0] = __builtin_fmaf(xe, bv[kk].x, pa[r][0]);
                    pa[r][1] = __builtin_fmaf(xe, bv[kk].y, pa[r][1]);
                    pa[r][2] = __builtin_fmaf(xe, bv[kk].z, pa[r][2]);
                    pa[r][3] = __builtin_fmaf(xe, bv[kk].w, pa[r][3]);
                    pb[r][0] = __builtin_fmaf(xo, bw[kk].x, pb[r][0]);
                    pb[r][1] = __builtin_fmaf(xo, bw[kk].y, pb[r][1]);
                    pb[r][2] = __builtin_fmaf(xo, bw[kk].z, pb[r][2]);
                    pb[r][3] = __builtin_fmaf(xo, bw[kk].w, pb[r][3]);
                }
        }
#pragma unroll
        for (int r = 0; r < 4; ++r) {
            float* orow = out + (size_t)(o * 512 + ht * 64 + ty * 4 + r) * 512;
            *(float4*)&orow[cb * 64 + tx * 4] =
                make_float4(pa[r][0] + pb[r][0], pa[r][1] + pb[r][1],
                            pa[r][2] + pb[r][2], pa[r][3] + pb[r][3]);
            *(float4*)&orow[256 + cb * 64 + tx * 4] =
                make_float4(pa[r][0] - pb[r][0], pa[r][1] - pb[r][1],
                            pa[r][2] - pb[r][2], pa[r][3] - pb[r][3]);
        }
    }
}

extern "C" void kernel_launch(void* const* d_in, const int* in_sizes, int n_in,
                              void* d_out, int out_size, void* d_ws, size_t ws_size,
                              hipStream_t stream) {
    const float* x  = (const float*)d_in[0];
    const float* Wr = (const float*)d_in[1];
    const float* Wi = (const float*)d_in[2];
    float* out = (float*)d_out;
    float* ws  = (float*)d_ws;

    float* F   = ws + OFF_F;
    float* FA2 = ws + OFF_FA2;
    float* GE2 = ws + OFF_GE2;
    float* GT  = ws + OFF_GT;
    float* XFp = ws + OFF_XFP;
    float* Gp  = ws + OFF_GP;

    build_table<<<128, 256, 0, stream>>>(F, FA2, GE2, GT);
    fusedAB<<<512, 256, 0, stream>>>(x, FA2, GT, XFp);
    stageC<<<512, 256, 0, stream>>>(XFp, Wr, Wi, Gp);
    fusedDE<<<512, 256, 0, stream>>>(F, Gp, GE2, out);
}

// Round 15
// 67.462 us; speedup vs baseline: 1.3366x; 1.0687x over previous
//
#include <hip/hip_runtime.h>
#include <math.h>

#define IN_CH 64
#define OUT_CH 64
#define M1 32
#define M2 32
#define HH 512
#define WW 512

// ---------------- workspace layout (floats) ----------------
// F   : [512][64]  cols 0..31 = cos(2pi k h/512), cols 32..63 = sin(...)
// FA2 : [256][64]  folded stage-A table. col j<32: re, j>=32: im; mode k=kperm(j&31);
//                  value = cos(2pi k w'/512) (re) or -sin (im). kperm(q)= q<16 ? 2q : 2(q-16)+1.
// GE2 : [64][256]  folded stage-E table. row c: c<16 re k=2c; 16..31 im k=2(c-16);
//                  32..47 re k=2(c-32)+1; 48..63 im k=2(c-48)+1. cos (re) / -sin (im).
// GT  : [64][512]  row j<32: cos(2pi j t/512); row j>=32: -sin(...)
// XFp : [64 i][8 ht][2 reim][32 kx][32 ky']  partial h-DFT
// Gp  : [2 ic][64 o][32 kx][32 ky][2]  partial channel-mix (REAL ky order)
static const size_t OFF_F   = 0;
static const size_t OFF_FA2 = 32768;
static const size_t OFF_GE2 = 49152;
static const size_t OFF_GT  = 65536;
static const size_t OFF_XFP = 98304;
static const size_t OFF_GP  = OFF_XFP + (size_t)64*8*2048;

__device__ __forceinline__ void gload16(const float* g, float* l) {
    __builtin_amdgcn_global_load_lds(
        (const __attribute__((address_space(1))) void*)g,
        (__attribute__((address_space(3))) void*)l, 16, 0, 0);
}

__global__ void build_table(float* __restrict__ F, float* __restrict__ FA2,
                            float* __restrict__ GE2, float* __restrict__ GT) {
    int idx = blockIdx.x * 256 + threadIdx.x;      // 0..32767
    const float c0 = 6.283185307179586f / 512.0f;
    {   // F + GT
        int w = idx >> 6, j = idx & 63, k = j & 31;
        int m = (k * w) & 511;
        float s, c;
        sincosf(c0 * (float)m, &s, &c);
        F[idx] = (j < 32) ? c : s;
        GT[(size_t)j * 512 + w] = (j < 32) ? c : -s;
    }
    if (idx < 16384) {   // FA2 [256][64]
        int wp = idx >> 6, j = idx & 63, q = j & 31;
        int k = (q < 16) ? 2 * q : 2 * (q - 16) + 1;
        int m = (k * wp) & 511;
        float s, c;
        sincosf(c0 * (float)m, &s, &c);
        FA2[idx] = (j < 32) ? c : -s;
    }
    if (idx < 16384) {   // GE2 [64][256]
        int cc = idx >> 8, wp = idx & 255;
        int base = cc & 15, parity = (cc >> 5) & 1, isIm = (cc >> 4) & 1;
        int k = 2 * base + parity;
        int m = (k * wp) & 511;
        float s, c;
        sincosf(c0 * (float)m, &s, &c);
        GE2[idx] = isIm ? -s : c;
    }
}

// Fused A+B (R7 verbatim). grid 512: i = bid>>3, ht = bid&7 (64 h-rows).
__global__ __launch_bounds__(256) void fusedAB(const float* __restrict__ x,
                                               const float* __restrict__ FA2,
                                               const float* __restrict__ GT,
                                               float* __restrict__ XFp) {
    __shared__ __align__(16) float xeo[8712];   // xe [64][68] @0; xo @4360; later xw [64][68]
    __shared__ __align__(16) float bs[4352];    // FA2 tiles linear [64][64]; later gt [64][68]
    int t = threadIdx.x, tx = t & 15, ty = t >> 4;
    int i = blockIdx.x >> 3, ht = blockIdx.x & 7;
    int h0 = ht * 64;
    float acc[4][4] = {};

    for (int tt = 0; tt < 4; ++tt) {
        int w0 = tt * 64;
#pragma unroll
        for (int p = 0; p < 4; ++p) {
            int flat = p * 1024 + t * 4;
            int rl = flat >> 6, c4 = flat & 63;
            const float* xr = &x[((size_t)i * 512 + h0 + rl) * 512 + w0 + c4];
            float4 a = *(const float4*)xr;
            float4 b = *(const float4*)(xr + 256);
            *(float4*)&xeo[rl * 68 + c4] =
                make_float4(a.x + b.x, a.y + b.y, a.z + b.z, a.w + b.w);
            *(float4*)&xeo[4360 + rl * 68 + c4] =
                make_float4(a.x - b.x, a.y - b.y, a.z - b.z, a.w - b.w);
            gload16(FA2 + (size_t)(w0 + rl) * 64 + c4, &bs[flat]);
        }
        __syncthreads();
        const float* xsb = &xeo[(tx & 4) ? 4360 : 0];   // odd-k cols read xo
#pragma unroll 4
        for (int k0 = 0; k0 < 64; k0 += 4) {
            float4 av[4], bv[4];
#pragma unroll
            for (int r = 0; r < 4; ++r)
                av[r] = *(const float4*)&xsb[(ty * 4 + r) * 68 + k0];
#pragma unroll
            for (int kk = 0; kk < 4; ++kk)
                bv[kk] = *(const float4*)&bs[(k0 + kk) * 64 + tx * 4];
#pragma unroll
            for (int kk = 0; kk < 4; ++kk)
#pragma unroll
                for (int r = 0; r < 4; ++r) {
                    float xk = (kk == 0) ? av[r].x : (kk == 1) ? av[r].y
                             : (kk == 2) ? av[r].z : av[r].w;
                    acc[r][0] = __builtin_fmaf(xk, bv[kk].x, acc[r][0]);
                    acc[r][1] = __builtin_fmaf(xk, bv[kk].y, acc[r][1]);
                    acc[r][2] = __builtin_fmaf(xk, bv[kk].z, acc[r][2]);
                    acc[r][3] = __builtin_fmaf(xk, bv[kk].w, acc[r][3]);
                }
        }
        __syncthreads();
    }

    // store Xw tile into xeo[0..] ([64][68]) and stage gt ([64][68]) into bs
#pragma unroll
    for (int r = 0; r < 4; ++r)
        *(float4*)&xeo[(ty * 4 + r) * 68 + tx * 4] =
            make_float4(acc[r][0], acc[r][1], acc[r][2], acc[r][3]);
#pragma unroll
    for (int p = 0; p < 4; ++p) {
        int flat = p * 1024 + t * 4;
        int j = flat >> 6, c4 = flat & 63;
        float4 g = *(const float4*)&GT[(size_t)j * 512 + h0 + c4];
        *(float4*)&bs[j * 68 + c4] = g;
    }
    __syncthreads();

    // Phase B
    int kx = t >> 3, kg = t & 7;
    float rr[4] = {0.f, 0.f, 0.f, 0.f};
    float ii[4] = {0.f, 0.f, 0.f, 0.f};
#pragma unroll 4
    for (int hh = 0; hh < 64; ++hh) {
        float cv = bs[kx * 68 + hh];
        float sv = bs[(kx + 32) * 68 + hh];          // = -sin
        float4 xr4 = *(const float4*)&xeo[hh * 68 + kg * 4];
        float4 xi4 = *(const float4*)&xeo[hh * 68 + 32 + kg * 4];
        rr[0] = __builtin_fmaf(xr4.x, cv, rr[0]); rr[0] = __builtin_fmaf(xi4.x, -sv, rr[0]);
        rr[1] = __builtin_fmaf(xr4.y, cv, rr[1]); rr[1] = __builtin_fmaf(xi4.y, -sv, rr[1]);
        rr[2] = __builtin_fmaf(xr4.z, cv, rr[2]); rr[2] = __builtin_fmaf(xi4.z, -sv, rr[2]);
        rr[3] = __builtin_fmaf(xr4.w, cv, rr[3]); rr[3] = __builtin_fmaf(xi4.w, -sv, rr[3]);
        ii[0] = __builtin_fmaf(xi4.x, cv, ii[0]); ii[0] = __builtin_fmaf(xr4.x, sv, ii[0]);
        ii[1] = __builtin_fmaf(xi4.y, cv, ii[1]); ii[1] = __builtin_fmaf(xr4.y, sv, ii[1]);
        ii[2] = __builtin_fmaf(xi4.z, cv, ii[2]); ii[2] = __builtin_fmaf(xr4.z, sv, ii[2]);
        ii[3] = __builtin_fmaf(xi4.w, cv, ii[3]); ii[3] = __builtin_fmaf(xr4.w, sv, ii[3]);
    }
    size_t base = ((size_t)i * 8 + ht) * 2048;
    *(float4*)&XFp[base + t * 4]        = make_float4(rr[0], rr[1], rr[2], rr[3]);
    *(float4*)&XFp[base + 1024 + t * 4] = make_float4(ii[0], ii[1], ii[2], ii[3]);
}

// Stage C: partial channel mix, i split in 2. grid 512.
// CHANGE vs R7: XFp ht-sum phase loads float4 (16 b128/thread) instead of 64 b32;
// thread = one (ip, ky'-quad) slot; transposed LDS write is 2-way aliased (free).
__global__ __launch_bounds__(256) void stageC(const float* __restrict__ XFp,
                                              const float* __restrict__ Wr,
                                              const float* __restrict__ Wi,
                                              float* __restrict__ Gp) {
    __shared__ float sxr[32][33];   // [ky'][i']
    __shared__ float sxi[32][33];
    int t = threadIdx.x;
    int kx = blockIdx.x & 31, oc = (blockIdx.x >> 5) & 7, ic = blockIdx.x >> 8;
    {
        int ip = t >> 3, kys4 = t & 7;       // ip 0..31, ky'-quad 0..7
        int i = ic * 32 + ip;
        float4 sr = make_float4(0.f, 0.f, 0.f, 0.f);
        float4 si = make_float4(0.f, 0.f, 0.f, 0.f);
#pragma unroll
        for (int ht = 0; ht < 8; ++ht) {
            size_t base = ((size_t)i * 8 + ht) * 2048 + kx * 32 + kys4 * 4;
            float4 r4 = *(const float4*)&XFp[base];
            float4 i4 = *(const float4*)&XFp[base + 1024];
            sr.x += r4.x; sr.y += r4.y; sr.z += r4.z; sr.w += r4.w;
            si.x += i4.x; si.y += i4.y; si.z += i4.z; si.w += i4.w;
        }
        sxr[kys4 * 4 + 0][ip] = sr.x; sxr[kys4 * 4 + 1][ip] = sr.y;
        sxr[kys4 * 4 + 2][ip] = sr.z; sxr[kys4 * 4 + 3][ip] = sr.w;
        sxi[kys4 * 4 + 0][ip] = si.x; sxi[kys4 * 4 + 1][ip] = si.y;
        sxi[kys4 * 4 + 2][ip] = si.z; sxi[kys4 * 4 + 3][ip] = si.w;
    }
    __syncthreads();
    int ky = t & 31, ol = t >> 5;            // REAL ky
    int kyp = (ky & 1) ? 16 + (ky >> 1) : (ky >> 1);
    int o = oc * 8 + ol;
    float lr = 0.f, li = 0.f;
#pragma unroll 4
    for (int ip = 0; ip < 32; ++ip) {
        float a = sxr[kyp][ip];
        float b = sxi[kyp][ip];
        size_t widx = ((size_t)(ic * 32 + ip) * 64 + o) * 1024 + kx * 32 + ky;
        float wrv = Wr[widx];
        float wiv = Wi[widx];
        lr = __builtin_fmaf(a, wrv, lr); lr = __builtin_fmaf(-b, wiv, lr);
        li = __builtin_fmaf(a, wiv, li); li = __builtin_fmaf(b, wrv, li);
    }
    size_t gidx = ((size_t)ic * 65536 + (size_t)o * 1024 + kx * 32 + ky) * 2;
    Gp[gidx]     = lr;
    Gp[gidx + 1] = li;
}

// Fused (reduceG +) D + E. grid 512: o = bid>>3, ht = bid&7. (R7 verbatim)
__global__ __launch_bounds__(256) void fusedDE(const float* __restrict__ Fc,
                                               const float* __restrict__ Gp,
                                               const float* __restrict__ GE2,
                                               float* __restrict__ out) {
    __shared__ __align__(16) float as[4096];   // F-tile (src-swizzled), then Z (XOR-swizzled)
    __shared__ __align__(16) float bs[4096];   // G [64m][64j'], then GE2 tiles
    int t = threadIdx.x, tx = t & 15, ty = t >> 4;
    int o = blockIdx.x >> 3, ht = blockIdx.x & 7;
    int sw = (ty & 3) << 2;

    const float2* gp2 = (const float2*)Gp;
#pragma unroll
    for (int q = 0; q < 4; ++q) {
        int iq = q * 256 + t;                 // 0..1023 = kx*32+ky (REAL ky)
        int ky = iq & 31, kx = iq >> 5;
        float2 g0 = gp2[(size_t)o * 1024 + iq];
        float2 g1 = gp2[(size_t)65536 + (size_t)o * 1024 + iq];
        float sc = ((ky == 0) ? 1.0f : 2.0f) * (1.0f / 262144.0f);
        float lr = (g0.x + g1.x) * sc;
        float li = (g0.y + g1.y) * sc;
        int pp = ky & 1, qq = ky >> 1;
        int colR = pp * 32 + qq, colI = pp * 32 + 16 + qq;
        bs[kx * 64 + colR]        = lr;
        bs[(32 + kx) * 64 + colR] = -li;
        bs[kx * 64 + colI]        = li;
        bs[(32 + kx) * 64 + colI] = lr;
    }
#pragma unroll
    for (int p = 0; p < 4; ++p) {
        int flat = p * 1024 + t * 4;
        int s16 = flat >> 2;
        int row = s16 >> 4, cp = s16 & 15;
        int cg = cp ^ ((row >> 2) & 3);
        gload16(Fc + (size_t)(ht * 64 + row) * 64 + cg * 4, &as[flat]);
    }
    __syncthreads();

    float acc[4][4] = {};
#pragma unroll 4
    for (int k0 = 0; k0 < 64; k0 += 4) {
        int ka = k0 ^ sw;
        float4 av[4], bv[4];
#pragma unroll
        for (int r = 0; r < 4; ++r)
            av[r] = *(const float4*)&as[(ty * 4 + r) * 64 + ka];
#pragma unroll
        for (int kk = 0; kk < 4; ++kk)
            bv[kk] = *(const float4*)&bs[(k0 + kk) * 64 + tx * 4];
#pragma unroll
        for (int kk = 0; kk < 4; ++kk)
#pragma unroll
            for (int r = 0; r < 4; ++r) {
                float xk = (kk == 0) ? av[r].x : (kk == 1) ? av[r].y
                         : (kk == 2) ? av[r].z : av[r].w;
                acc[r][0] = __builtin_fmaf(xk, bv[kk].x, acc[r][0]);
                acc[r][1] = __builtin_fmaf(xk, bv[kk].y, acc[r][1]);
                acc[r][2] = __builtin_fmaf(xk, bv[kk].z, acc[r][2]);
                acc[r][3] = __builtin_fmaf(xk, bv[kk].w, acc[r][3]);
            }
    }
    __syncthreads();

#pragma unroll
    for (int r = 0; r < 4; ++r) {
        int row = ty * 4 + r;
        int cg = tx ^ ((row >> 2) & 3);
        *(float4*)&as[row * 64 + cg * 4] =
            make_float4(acc[r][0], acc[r][1], acc[r][2], acc[r][3]);
    }

    for (int cb = 0; cb < 4; ++cb) {
        __syncthreads();
#pragma unroll
        for (int p = 0; p < 4; ++p) {
            int flat = p * 1024 + t * 4;
            int brow = flat >> 6, bcol = flat & 63;
            gload16(GE2 + (size_t)brow * 256 + cb * 64 + bcol, &bs[flat]);
        }
        __syncthreads();
        float pa[4][4] = {}, pb[4][4] = {};
#pragma unroll 4
        for (int k0 = 0; k0 < 32; k0 += 4) {
            int kae = k0 ^ sw, kao = 32 + (k0 ^ sw);
            float4 av[4], bv[4], aw[4], bw[4];
#pragma unroll
            for (int r = 0; r < 4; ++r) {
                av[r] = *(const float4*)&as[(ty * 4 + r) * 64 + kae];
                aw[r] = *(const float4*)&as[(ty * 4 + r) * 64 + kao];
            }
#pragma unroll
            for (int kk = 0; kk < 4; ++kk) {
                bv[kk] = *(const float4*)&bs[(k0 + kk) * 64 + tx * 4];
                bw[kk] = *(const float4*)&bs[(32 + k0 + kk) * 64 + tx * 4];
            }
#pragma unroll
            for (int kk = 0; kk < 4; ++kk)
#pragma unroll
                for (int r = 0; r < 4; ++r) {
                    float xe = (kk == 0) ? av[r].x : (kk == 1) ? av[r].y
                             : (kk == 2) ? av[r].z : av[r].w;
                    float xo = (kk == 0) ? aw[r].x : (kk == 1) ? aw[r].y
                             : (kk == 2) ? aw[r].z : aw[r].w;
                    pa[r][0] = __builtin_fmaf(xe, bv[kk].x, pa[r][0]);
                    pa[r][1] = __builtin_fmaf(xe, bv[kk].y, pa[r][1]);
                    pa[r][2] = __builtin_fmaf(xe, bv[kk].z, pa[r][2]);
                    pa[r][3] = __builtin_fmaf(xe, bv[kk].w, pa[r][3]);
                    pb[r][0] = __builtin_fmaf(xo, bw[kk].x, pb[r][0]);
                    pb[r][1] = __builtin_fmaf(xo, bw[kk].y, pb[r][1]);
                    pb[r][2] = __builtin_fmaf(xo, bw[kk].z, pb[r][2]);
                    pb[r][3] = __builtin_fmaf(xo, bw[kk].w, pb[r][3]);
                }
        }
#pragma unroll
        for (int r = 0; r < 4; ++r) {
            float* orow = out + (size_t)(o * 512 + ht * 64 + ty * 4 + r) * 512;
            *(float4*)&orow[cb * 64 + tx * 4] =
                make_float4(pa[r][0] + pb[r][0], pa[r][1] + pb[r][1],
                            pa[r][2] + pb[r][2], pa[r][3] + pb[r][3]);
            *(float4*)&orow[256 + cb * 64 + tx * 4] =
                make_float4(pa[r][0] - pb[r][0], pa[r][1] - pb[r][1],
                            pa[r][2] - pb[r][2], pa[r][3] - pb[r][3]);
        }
    }
}

extern "C" void kernel_launch(void* const* d_in, const int* in_sizes, int n_in,
                              void* d_out, int out_size, void* d_ws, size_t ws_size,
                              hipStream_t stream) {
    const float* x  = (const float*)d_in[0];
    const float* Wr = (const float*)d_in[1];
    const float* Wi = (const float*)d_in[2];
    float* out = (float*)d_out;
    float* ws  = (float*)d_ws;

    float* F   = ws + OFF_F;
    float* FA2 = ws + OFF_FA2;
    float* GE2 = ws + OFF_GE2;
    float* GT  = ws + OFF_GT;
    float* XFp = ws + OFF_XFP;
    float* Gp  = ws + OFF_GP;

    build_table<<<128, 256, 0, stream>>>(F, FA2, GE2, GT);
    fusedAB<<<512, 256, 0, stream>>>(x, FA2, GT, XFp);
    stageC<<<512, 256, 0, stream>>>(XFp, Wr, Wi, Gp);
    fusedDE<<<512, 256, 0, stream>>>(F, Gp, GE2, out);
}

// Round 16
// 67.349 us; speedup vs baseline: 1.3388x; 1.0017x over previous
//
#include <hip/hip_runtime.h>
#include <math.h>

#define IN_CH 64
#define OUT_CH 64
#define M1 32
#define M2 32
#define HH 512
#define WW 512

// ---------------- workspace layout (floats) ----------------
// F   : [512][64]  cols 0..31 = cos(2pi k h/512), cols 32..63 = sin(...)
// FA2 : [256][64]  folded stage-A table. col j<32: re, j>=32: im; mode k=kperm(j&31);
//                  value = cos(2pi k w'/512) (re) or -sin (im). kperm(q)= q<16 ? 2q : 2(q-16)+1.
// GE2 : [64][256]  folded stage-E table. row c: c<16 re k=2c; 16..31 im k=2(c-16);
//                  32..47 re k=2(c-32)+1; 48..63 im k=2(c-48)+1. cos (re) / -sin (im).
// GT  : [64][512]  row j<32: cos(2pi j t/512); row j>=32: -sin(...)
// XFp : [64 i][8 ht][2 reim][32 kx][32 ky']  partial h-DFT
// Gp  : [2 ic][64 o][32 kx][32 ky][2]  partial channel-mix (REAL ky order)
static const size_t OFF_F   = 0;
static const size_t OFF_FA2 = 32768;
static const size_t OFF_GE2 = 49152;
static const size_t OFF_GT  = 65536;
static const size_t OFF_XFP = 98304;
static const size_t OFF_GP  = OFF_XFP + (size_t)64*8*2048;

__device__ __forceinline__ void gload16(const float* g, float* l) {
    __builtin_amdgcn_global_load_lds(
        (const __attribute__((address_space(1))) void*)g,
        (__attribute__((address_space(3))) void*)l, 16, 0, 0);
}

__global__ void build_table(float* __restrict__ F, float* __restrict__ FA2,
                            float* __restrict__ GE2, float* __restrict__ GT) {
    int idx = blockIdx.x * 256 + threadIdx.x;      // 0..32767
    const float c0 = 6.283185307179586f / 512.0f;
    {   // F + GT
        int w = idx >> 6, j = idx & 63, k = j & 31;
        int m = (k * w) & 511;
        float s, c;
        sincosf(c0 * (float)m, &s, &c);
        F[idx] = (j < 32) ? c : s;
        GT[(size_t)j * 512 + w] = (j < 32) ? c : -s;
    }
    if (idx < 16384) {   // FA2 [256][64]
        int wp = idx >> 6, j = idx & 63, q = j & 31;
        int k = (q < 16) ? 2 * q : 2 * (q - 16) + 1;
        int m = (k * wp) & 511;
        float s, c;
        sincosf(c0 * (float)m, &s, &c);
        FA2[idx] = (j < 32) ? c : -s;
    }
    if (idx < 16384) {   // GE2 [64][256]
        int cc = idx >> 8, wp = idx & 255;
        int base = cc & 15, parity = (cc >> 5) & 1, isIm = (cc >> 4) & 1;
        int k = 2 * base + parity;
        int m = (k * wp) & 511;
        float s, c;
        sincosf(c0 * (float)m, &s, &c);
        GE2[idx] = isIm ? -s : c;
    }
}

// Fused A+B (R7 verbatim). grid 512: i = bid>>3, ht = bid&7 (64 h-rows).
__global__ __launch_bounds__(256) void fusedAB(const float* __restrict__ x,
                                               const float* __restrict__ FA2,
                                               const float* __restrict__ GT,
                                               float* __restrict__ XFp) {
    __shared__ __align__(16) float xeo[8712];   // xe [64][68] @0; xo @4360; later xw [64][68]
    __shared__ __align__(16) float bs[4352];    // FA2 tiles linear [64][64]; later gt [64][68]
    int t = threadIdx.x, tx = t & 15, ty = t >> 4;
    int i = blockIdx.x >> 3, ht = blockIdx.x & 7;
    int h0 = ht * 64;
    float acc[4][4] = {};

    for (int tt = 0; tt < 4; ++tt) {
        int w0 = tt * 64;
#pragma unroll
        for (int p = 0; p < 4; ++p) {
            int flat = p * 1024 + t * 4;
            int rl = flat >> 6, c4 = flat & 63;
            const float* xr = &x[((size_t)i * 512 + h0 + rl) * 512 + w0 + c4];
            float4 a = *(const float4*)xr;
            float4 b = *(const float4*)(xr + 256);
            *(float4*)&xeo[rl * 68 + c4] =
                make_float4(a.x + b.x, a.y + b.y, a.z + b.z, a.w + b.w);
            *(float4*)&xeo[4360 + rl * 68 + c4] =
                make_float4(a.x - b.x, a.y - b.y, a.z - b.z, a.w - b.w);
            gload16(FA2 + (size_t)(w0 + rl) * 64 + c4, &bs[flat]);
        }
        __syncthreads();
        const float* xsb = &xeo[(tx & 4) ? 4360 : 0];   // odd-k cols read xo
#pragma unroll 4
        for (int k0 = 0; k0 < 64; k0 += 4) {
            float4 av[4], bv[4];
#pragma unroll
            for (int r = 0; r < 4; ++r)
                av[r] = *(const float4*)&xsb[(ty * 4 + r) * 68 + k0];
#pragma unroll
            for (int kk = 0; kk < 4; ++kk)
                bv[kk] = *(const float4*)&bs[(k0 + kk) * 64 + tx * 4];
#pragma unroll
            for (int kk = 0; kk < 4; ++kk)
#pragma unroll
                for (int r = 0; r < 4; ++r) {
                    float xk = (kk == 0) ? av[r].x : (kk == 1) ? av[r].y
                             : (kk == 2) ? av[r].z : av[r].w;
                    acc[r][0] = __builtin_fmaf(xk, bv[kk].x, acc[r][0]);
                    acc[r][1] = __builtin_fmaf(xk, bv[kk].y, acc[r][1]);
                    acc[r][2] = __builtin_fmaf(xk, bv[kk].z, acc[r][2]);
                    acc[r][3] = __builtin_fmaf(xk, bv[kk].w, acc[r][3]);
                }
        }
        __syncthreads();
    }

    // store Xw tile into xeo[0..] ([64][68]) and stage gt ([64][68]) into bs
#pragma unroll
    for (int r = 0; r < 4; ++r)
        *(float4*)&xeo[(ty * 4 + r) * 68 + tx * 4] =
            make_float4(acc[r][0], acc[r][1], acc[r][2], acc[r][3]);
#pragma unroll
    for (int p = 0; p < 4; ++p) {
        int flat = p * 1024 + t * 4;
        int j = flat >> 6, c4 = flat & 63;
        float4 g = *(const float4*)&GT[(size_t)j * 512 + h0 + c4];
        *(float4*)&bs[j * 68 + c4] = g;
    }
    __syncthreads();

    // Phase B
    int kx = t >> 3, kg = t & 7;
    float rr[4] = {0.f, 0.f, 0.f, 0.f};
    float ii[4] = {0.f, 0.f, 0.f, 0.f};
#pragma unroll 4
    for (int hh = 0; hh < 64; ++hh) {
        float cv = bs[kx * 68 + hh];
        float sv = bs[(kx + 32) * 68 + hh];          // = -sin
        float4 xr4 = *(const float4*)&xeo[hh * 68 + kg * 4];
        float4 xi4 = *(const float4*)&xeo[hh * 68 + 32 + kg * 4];
        rr[0] = __builtin_fmaf(xr4.x, cv, rr[0]); rr[0] = __builtin_fmaf(xi4.x, -sv, rr[0]);
        rr[1] = __builtin_fmaf(xr4.y, cv, rr[1]); rr[1] = __builtin_fmaf(xi4.y, -sv, rr[1]);
        rr[2] = __builtin_fmaf(xr4.z, cv, rr[2]); rr[2] = __builtin_fmaf(xi4.z, -sv, rr[2]);
        rr[3] = __builtin_fmaf(xr4.w, cv, rr[3]); rr[3] = __builtin_fmaf(xi4.w, -sv, rr[3]);
        ii[0] = __builtin_fmaf(xi4.x, cv, ii[0]); ii[0] = __builtin_fmaf(xr4.x, sv, ii[0]);
        ii[1] = __builtin_fmaf(xi4.y, cv, ii[1]); ii[1] = __builtin_fmaf(xr4.y, sv, ii[1]);
        ii[2] = __builtin_fmaf(xi4.z, cv, ii[2]); ii[2] = __builtin_fmaf(xr4.z, sv, ii[2]);
        ii[3] = __builtin_fmaf(xi4.w, cv, ii[3]); ii[3] = __builtin_fmaf(xr4.w, sv, ii[3]);
    }
    size_t base = ((size_t)i * 8 + ht) * 2048;
    *(float4*)&XFp[base + t * 4]        = make_float4(rr[0], rr[1], rr[2], rr[3]);
    *(float4*)&XFp[base + 1024 + t * 4] = make_float4(ii[0], ii[1], ii[2], ii[3]);
}

// Stage C: partial channel mix, i split in 2. grid 512.
// CHANGE vs R7: XFp ht-sum phase loads float4 (16 b128/thread) instead of 64 b32;
// thread = one (ip, ky'-quad) slot; transposed LDS write is 2-way aliased (free).
__global__ __launch_bounds__(256) void stageC(const float* __restrict__ XFp,
                                              const float* __restrict__ Wr,
                                              const float* __restrict__ Wi,
                                              float* __restrict__ Gp) {
    __shared__ float sxr[32][33];   // [ky'][i']
    __shared__ float sxi[32][33];
    int t = threadIdx.x;
    int kx = blockIdx.x & 31, oc = (blockIdx.x >> 5) & 7, ic = blockIdx.x >> 8;
    {
        int ip = t >> 3, kys4 = t & 7;       // ip 0..31, ky'-quad 0..7
        int i = ic * 32 + ip;
        float4 sr = make_float4(0.f, 0.f, 0.f, 0.f);
        float4 si = make_float4(0.f, 0.f, 0.f, 0.f);
#pragma unroll
        for (int ht = 0; ht < 8; ++ht) {
            size_t base = ((size_t)i * 8 + ht) * 2048 + kx * 32 + kys4 * 4;
            float4 r4 = *(const float4*)&XFp[base];
            float4 i4 = *(const float4*)&XFp[base + 1024];
            sr.x += r4.x; sr.y += r4.y; sr.z += r4.z; sr.w += r4.w;
            si.x += i4.x; si.y += i4.y; si.z += i4.z; si.w += i4.w;
        }
        sxr[kys4 * 4 + 0][ip] = sr.x; sxr[kys4 * 4 + 1][ip] = sr.y;
        sxr[kys4 * 4 + 2][ip] = sr.z; sxr[kys4 * 4 + 3][ip] = sr.w;
        sxi[kys4 * 4 + 0][ip] = si.x; sxi[kys4 * 4 + 1][ip] = si.y;
        sxi[kys4 * 4 + 2][ip] = si.z; sxi[kys4 * 4 + 3][ip] = si.w;
    }
    __syncthreads();
    int ky = t & 31, ol = t >> 5;            // REAL ky
    int kyp = (ky & 1) ? 16 + (ky >> 1) : (ky >> 1);
    int o = oc * 8 + ol;
    float lr = 0.f, li = 0.f;
#pragma unroll 4
    for (int ip = 0; ip < 32; ++ip) {
        float a = sxr[kyp][ip];
        float b = sxi[kyp][ip];
        size_t widx = ((size_t)(ic * 32 + ip) * 64 + o) * 1024 + kx * 32 + ky;
        float wrv = Wr[widx];
        float wiv = Wi[widx];
        lr = __builtin_fmaf(a, wrv, lr); lr = __builtin_fmaf(-b, wiv, lr);
        li = __builtin_fmaf(a, wiv, li); li = __builtin_fmaf(b, wrv, li);
    }
    size_t gidx = ((size_t)ic * 65536 + (size_t)o * 1024 + kx * 32 + ky) * 2;
    Gp[gidx]     = lr;
    Gp[gidx + 1] = li;
}

// Fused (reduceG +) D + E. grid 512: o = bid>>3, ht = bid&7. (R7 verbatim)
__global__ __launch_bounds__(256) void fusedDE(const float* __restrict__ Fc,
                                               const float* __restrict__ Gp,
                                               const float* __restrict__ GE2,
                                               float* __restrict__ out) {
    __shared__ __align__(16) float as[4096];   // F-tile (src-swizzled), then Z (XOR-swizzled)
    __shared__ __align__(16) float bs[4096];   // G [64m][64j'], then GE2 tiles
    int t = threadIdx.x, tx = t & 15, ty = t >> 4;
    int o = blockIdx.x >> 3, ht = blockIdx.x & 7;
    int sw = (ty & 3) << 2;

    const float2* gp2 = (const float2*)Gp;
#pragma unroll
    for (int q = 0; q < 4; ++q) {
        int iq = q * 256 + t;                 // 0..1023 = kx*32+ky (REAL ky)
        int ky = iq & 31, kx = iq >> 5;
        float2 g0 = gp2[(size_t)o * 1024 + iq];
        float2 g1 = gp2[(size_t)65536 + (size_t)o * 1024 + iq];
        float sc = ((ky == 0) ? 1.0f : 2.0f) * (1.0f / 262144.0f);
        float lr = (g0.x + g1.x) * sc;
        float li = (g0.y + g1.y) * sc;
        int pp = ky & 1, qq = ky >> 1;
        int colR = pp * 32 + qq, colI = pp * 32 + 16 + qq;
        bs[kx * 64 + colR]        = lr;
        bs[(32 + kx) * 64 + colR] = -li;
        bs[kx * 64 + colI]        = li;
        bs[(32 + kx) * 64 + colI] = lr;
    }
#pragma unroll
    for (int p = 0; p < 4; ++p) {
        int flat = p * 1024 + t * 4;
        int s16 = flat >> 2;
        int row = s16 >> 4, cp = s16 & 15;
        int cg = cp ^ ((row >> 2) & 3);
        gload16(Fc + (size_t)(ht * 64 + row) * 64 + cg * 4, &as[flat]);
    }
    __syncthreads();

    float acc[4][4] = {};
#pragma unroll 4
    for (int k0 = 0; k0 < 64; k0 += 4) {
        int ka = k0 ^ sw;
        float4 av[4], bv[4];
#pragma unroll
        for (int r = 0; r < 4; ++r)
            av[r] = *(const float4*)&as[(ty * 4 + r) * 64 + ka];
#pragma unroll
        for (int kk = 0; kk < 4; ++kk)
            bv[kk] = *(const float4*)&bs[(k0 + kk) * 64 + tx * 4];
#pragma unroll
        for (int kk = 0; kk < 4; ++kk)
#pragma unroll
            for (int r = 0; r < 4; ++r) {
                float xk = (kk == 0) ? av[r].x : (kk == 1) ? av[r].y
                         : (kk == 2) ? av[r].z : av[r].w;
                acc[r][0] = __builtin_fmaf(xk, bv[kk].x, acc[r][0]);
                acc[r][1] = __builtin_fmaf(xk, bv[kk].y, acc[r][1]);
                acc[r][2] = __builtin_fmaf(xk, bv[kk].z, acc[r][2]);
                acc[r][3] = __builtin_fmaf(xk, bv[kk].w, acc[r][3]);
            }
    }
    __syncthreads();

#pragma unroll
    for (int r = 0; r < 4; ++r) {
        int row = ty * 4 + r;
        int cg = tx ^ ((row >> 2) & 3);
        *(float4*)&as[row * 64 + cg * 4] =
            make_float4(acc[r][0], acc[r][1], acc[r][2], acc[r][3]);
    }

    for (int cb = 0; cb < 4; ++cb) {
        __syncthreads();
#pragma unroll
        for (int p = 0; p < 4; ++p) {
            int flat = p * 1024 + t * 4;
            int brow = flat >> 6, bcol = flat & 63;
            gload16(GE2 + (size_t)brow * 256 + cb * 64 + bcol, &bs[flat]);
        }
        __syncthreads();
        float pa[4][4] = {}, pb[4][4] = {};
#pragma unroll 4
        for (int k0 = 0; k0 < 32; k0 += 4) {
            int kae = k0 ^ sw, kao = 32 + (k0 ^ sw);
            float4 av[4], bv[4], aw[4], bw[4];
#pragma unroll
            for (int r = 0; r < 4; ++r) {
                av[r] = *(const float4*)&as[(ty * 4 + r) * 64 + kae];
                aw[r] = *(const float4*)&as[(ty * 4 + r) * 64 + kao];
            }
#pragma unroll
            for (int kk = 0; kk < 4; ++kk) {
                bv[kk] = *(const float4*)&bs[(k0 + kk) * 64 + tx * 4];
                bw[kk] = *(const float4*)&bs[(32 + k0 + kk) * 64 + tx * 4];
            }
#pragma unroll
            for (int kk = 0; kk < 4; ++kk)
#pragma unroll
                for (int r = 0; r < 4; ++r) {
                    float xe = (kk == 0) ? av[r].x : (kk == 1) ? av[r].y
                             : (kk == 2) ? av[r].z : av[r].w;
                    float xo = (kk == 0) ? aw[r].x : (kk == 1) ? aw[r].y
                             : (kk == 2) ? aw[r].z : aw[r].w;
                    pa[r][0] = __builtin_fmaf(xe, bv[kk].x, pa[r][0]);
                    pa[r][1] = __builtin_fmaf(xe, bv[kk].y, pa[r][1]);
                    pa[r][2] = __builtin_fmaf(xe, bv[kk].z, pa[r][2]);
                    pa[r][3] = __builtin_fmaf(xe, bv[kk].w, pa[r][3]);
                    pb[r][0] = __builtin_fmaf(xo, bw[kk].x, pb[r][0]);
                    pb[r][1] = __builtin_fmaf(xo, bw[kk].y, pb[r][1]);
                    pb[r][2] = __builtin_fmaf(xo, bw[kk].z, pb[r][2]);
                    pb[r][3] = __builtin_fmaf(xo, bw[kk].w, pb[r][3]);
                }
        }
#pragma unroll
        for (int r = 0; r < 4; ++r) {
            float* orow = out + (size_t)(o * 512 + ht * 64 + ty * 4 + r) * 512;
            *(float4*)&orow[cb * 64 + tx * 4] =
                make_float4(pa[r][0] + pb[r][0], pa[r][1] + pb[r][1],
                            pa[r][2] + pb[r][2], pa[r][3] + pb[r][3]);
            *(float4*)&orow[256 + cb * 64 + tx * 4] =
                make_float4(pa[r][0] - pb[r][0], pa[r][1] - pb[r][1],
                            pa[r][2] - pb[r][2], pa[r][3] - pb[r][3]);
        }
    }
}

extern "C" void kernel_launch(void* const* d_in, const int* in_sizes, int n_in,
                              void* d_out, int out_size, void* d_ws, size_t ws_size,
                              hipStream_t stream) {
    const float* x  = (const float*)d_in[0];
    const float* Wr = (const float*)d_in[1];
    const float* Wi = (const float*)d_in[2];
    float* out = (float*)d_out;
    float* ws  = (float*)d_ws;

    float* F   = ws + OFF_F;
    float* FA2 = ws + OFF_FA2;
    float* GE2 = ws + OFF_GE2;
    float* GT  = ws + OFF_GT;
    float* XFp = ws + OFF_XFP;
    float* Gp  = ws + OFF_GP;

    build_table<<<128, 256, 0, stream>>>(F, FA2, GE2, GT);
    fusedAB<<<512, 256, 0, stream>>>(x, FA2, GT, XFp);
    stageC<<<512, 256, 0, stream>>>(XFp, Wr, Wi, Gp);
    fusedDE<<<512, 256, 0, stream>>>(F, Gp, GE2, out);
}